// Round 4
// baseline (312.908 us; speedup 1.0000x reference)
//
#include <hip/hip_runtime.h>

#define NN 100000
#define NE 1600000
#define BN_EPS 1e-5f
#define NBKT 6250         // fine buckets of 16 nodes (g = dst>>4)
#define FCAP 416          // slab capacity per fine bucket (mean 256, +10 sigma)
#define FSTR 72           // LDS F-tile row stride in shorts (144B rows, 16B-aligned)
#define NFRAG 48          // packed weight fragments

typedef short s8v __attribute__((ext_vector_type(8)));
typedef float f4v __attribute__((ext_vector_type(4)));
typedef float f2v __attribute__((ext_vector_type(2)));
typedef unsigned u4v __attribute__((ext_vector_type(4)));

__device__ __forceinline__ float bf2f(unsigned short u) {
  union { unsigned u; float f; } v; v.u = ((unsigned)u) << 16; return v.f;
}
__device__ __forceinline__ unsigned fbits(float f) {
  union { float f; unsigned u; } v; v.f = f; return v.u;
}
__device__ __forceinline__ float bcast(unsigned u) {
  union { unsigned u; float f; } v; v.u = u; return v.f;
}
// round-half-up bf16 (ties differ from RNE with prob 2^-16 — negligible)
__device__ __forceinline__ unsigned short f2bf(float f) {
  return (unsigned short)((fbits(f) + 0x8000u) >> 16);
}
__device__ __forceinline__ s8v ldfrag(const unsigned short* __restrict__ pack,
                                      int f, int lane) {
  return *(const s8v*)(pack + ((size_t)f * 64 + lane) * 8);
}
// prelu(x) = max(x, a*x) — exact for 0 <= a <= 1 (a == 0.25 here)
__device__ __forceinline__ float prelu_m(float x, float a) { return fmaxf(x, a * x); }

// h1 on one dword pair (2 bf16 elems of F and G); RNE pack via v_cvt_pk_bf16_f32
__device__ __forceinline__ unsigned h1pair(unsigned fd, unsigned gd, float al) {
  f2v fv = { bcast(fd << 16), bcast(fd & 0xFFFF0000u) };
  f2v gv = { bcast(gd << 16), bcast(gd & 0xFFFF0000u) };
  f2v s = fv + gv;
  f2v t = s * al;
  float m0 = fmaxf(s.x, t.x);
  float m1 = fmaxf(s.y, t.y);
  unsigned rr;
  asm("v_cvt_pk_bf16_f32 %0, %1, %2" : "=v"(rr) : "v"(m0), "v"(m1));
  return rr;
}

#define MFMA16(a, b, c) __builtin_amdgcn_mfma_f32_16x16x32_bf16((a), (b), (c), 0, 0, 0)

// ---------------------------------------------------------------------------
// Weight pack (one-shot) + BN-partial zeroing.
// frag map: 0..7 W1 top | 8..15 W1 bot | 16..23 W2 | 24..39 W3 | 40..47 W4
// ---------------------------------------------------------------------------
__global__ __launch_bounds__(256) void pack_kernel(
    const float* __restrict__ W1, const float* __restrict__ W2,
    const float* __restrict__ W3, const float* __restrict__ W4,
    unsigned short* __restrict__ pack, float* __restrict__ part)
{
  if (threadIdx.x < 128) part[threadIdx.x] = 0.f;
  for (int it = threadIdx.x; it < NFRAG * 64; it += 256) {
    const int f = it >> 6;
    const int lane = it & 63;
    const int q = lane >> 4, r = lane & 15;
    const float* src; int rowoff, fi;
    if (f < 8)       { src = W1; rowoff = 0;  fi = f; }
    else if (f < 16) { src = W1; rowoff = 64; fi = f - 8; }
    else if (f < 24) { src = W2; rowoff = 0;  fi = f - 16; }
    else if (f < 40) { src = W3; rowoff = 0;  fi = f - 24; }
    else             { src = W4; rowoff = 0;  fi = f - 40; }
    const int kk = fi >> 2, nt = fi & 3;
    unsigned short tmp[8];
#pragma unroll
    for (int j = 0; j < 8; ++j)
      tmp[j] = f2bf(src[(size_t)(rowoff + kk * 32 + q * 8 + j) * 64 + nt * 16 + r]);
    *(s8v*)(pack + ((size_t)f * 64 + lane) * 8) = *(const s8v*)tmp;
  }
}

// ---------------------------------------------------------------------------
// Pre-GEMM: F = X@W1top + b1 (bias folded), G = X@W1bot, XB = bf16(X)
// ---------------------------------------------------------------------------
__global__ __launch_bounds__(256) void pre_gemm_kernel(
    const float* __restrict__ x, const unsigned short* __restrict__ pack,
    const float* __restrict__ b1,
    unsigned short* __restrict__ F, unsigned short* __restrict__ G,
    unsigned short* __restrict__ XB)
{
  const int lane = threadIdx.x & 63;
  const int wv   = threadIdx.x >> 6;
  const int q    = lane >> 4;
  const int r    = lane & 15;
  const int nw   = gridDim.x * 4;
  const int wid  = blockIdx.x * 4 + wv;

  s8v Bt[2][4], Bb[2][4];
#pragma unroll
  for (int kk = 0; kk < 2; ++kk)
#pragma unroll
    for (int nt = 0; nt < 4; ++nt) {
      Bt[kk][nt] = ldfrag(pack, kk * 4 + nt, lane);
      Bb[kk][nt] = ldfrag(pack, 8 + kk * 4 + nt, lane);
    }
  float b1c[4];
#pragma unroll
  for (int nt = 0; nt < 4; ++nt) b1c[nt] = b1[nt * 16 + r];

  for (int t = wid; t < NN / 16; t += nw) {
    const int n = t * 16 + r;
    const f4v* xp = (const f4v*)(x + (size_t)n * 64);
    f4v x0 = xp[q * 2],     x1 = xp[q * 2 + 1];
    f4v x2 = xp[8 + q * 2], x3 = xp[8 + q * 2 + 1];
    s8v a0, a1v;
#pragma unroll
    for (int j = 0; j < 4; ++j) {
      a0[j]      = (short)f2bf(x0[j]);
      a0[4 + j]  = (short)f2bf(x1[j]);
      a1v[j]     = (short)f2bf(x2[j]);
      a1v[4 + j] = (short)f2bf(x3[j]);
    }
    *(s8v*)(XB + (size_t)n * 64 + q * 8)      = a0;
    *(s8v*)(XB + (size_t)n * 64 + 32 + q * 8) = a1v;

    f4v aF[4], aG[4];
#pragma unroll
    for (int nt = 0; nt < 4; ++nt) {
      f4v c = {0.f, 0.f, 0.f, 0.f};
      c = MFMA16(a0,  Bt[0][nt], c);
      c = MFMA16(a1v, Bt[1][nt], c);
      aF[nt] = c;
      f4v d = {0.f, 0.f, 0.f, 0.f};
      d = MFMA16(a0,  Bb[0][nt], d);
      d = MFMA16(a1v, Bb[1][nt], d);
      aG[nt] = d;
    }
#pragma unroll
    for (int nt = 0; nt < 4; ++nt)
#pragma unroll
      for (int rg = 0; rg < 4; ++rg) {
        const size_t idx = (size_t)(t * 16 + q * 4 + rg) * 64 + nt * 16 + r;
        F[idx] = f2bf(aF[nt][rg] + b1c[nt]);
        G[idx] = f2bf(aG[nt][rg]);
      }
  }
}

// ---------------------------------------------------------------------------
// Single-pass edge scatter: one returning atomic per edge reserves a slot
// in the destination's FINE-bucket slab (replaces the old coarse-scatter +
// per-slab counting-sort pair; sort_b ran only 196 blocks = <1/CU).
// word = (src << 9) | (dst & 511); edge_agg uses w>>9 and w&15 only.
// Slack beyond cnt[g] is uninitialized: edge_agg clamps gathered indices.
// ---------------------------------------------------------------------------
__global__ __launch_bounds__(256) void scatter_kernel(
    const int* __restrict__ srcp, const int* __restrict__ dstp,
    int* __restrict__ cnt, int* __restrict__ ebuf)
{
  const int i = blockIdx.x * 256 + threadIdx.x;
  const int d = dstp[i];
  const int s = srcp[i];
  const int g = d >> 4;
  const int p = atomicAdd(&cnt[g], 1);
  if (p < FCAP) ebuf[(size_t)g * FCAP + p] = (s << 9) | (d & 511);
}

// ---------------------------------------------------------------------------
// Edge MLP + aggregation: one wave per 16-node fine bucket. RMW-free.
// v5 = v4 (in-register h2 via swapped MFMA + cvt_pk + permlane32/16) with:
//  - fine-bucket slab addressing (start = g*FCAP, end from cnt[]),
//  - unclamped LOADW (slack garbage is made safe by umin on src index;
//    dloc-mask already zeroes those columns in the agg MFMA, and clamped
//    indices point at valid finite data so no NaN can enter),
//  - packed-16-bit sA indicator build (pk_min/pk_sub/and) replacing the
//    per-element s8v insert chain.
// ---------------------------------------------------------------------------
__global__ __launch_bounds__(256) void edge_agg_kernel(
    const unsigned short* __restrict__ F, const unsigned short* __restrict__ G,
    const int* __restrict__ ebuf, const int* __restrict__ cnt,
    const unsigned short* __restrict__ pack,
    const float* __restrict__ a1p,
    const float* __restrict__ b2, const float* __restrict__ a2p,
    unsigned short* __restrict__ aggb)
{
  const int lane = threadIdx.x & 63;
  const int wv   = threadIdx.x >> 6;
  const int q    = lane >> 4;
  const int r    = lane & 15;

  __shared__ __align__(16) unsigned short ftl[4][16 * FSTR];   // per-wave F tile
  __shared__ __align__(16) unsigned short dbf[4][32];          // per-wave dloc
  unsigned short* ft = ftl[wv];
  unsigned short* db = dbf[wv];

  const int g = blockIdx.x * 4 + wv;
  if (g >= NBKT) return;                      // no block barriers below: safe

  const int start = g * FCAP;
  int cg = cnt[g]; cg = cg < FCAP ? cg : FCAP;
  const int end = start + cg;
  const int nbase = g * 16;

  s8v W2T[2][4];
#pragma unroll
  for (int kk = 0; kk < 2; ++kk)
#pragma unroll
    for (int ot = 0; ot < 4; ++ot)
      W2T[kk][ot] = ldfrag(pack, 16 + kk * 4 + ot, lane);

  // bias for swapped MFMA: C[row=edge][col=feat] -> per-lane scalar per ot
  float b2c[4];
#pragma unroll
  for (int ot = 0; ot < 4; ++ot) b2c[ot] = b2[ot * 16 + r];

  // uniform scalars -> SGPR
  union { float f; int i; } ua1, ua2;
  ua1.f = a1p[0]; ua1.i = __builtin_amdgcn_readfirstlane(ua1.i);
  ua2.f = a2p[0]; ua2.i = __builtin_amdgcn_readfirstlane(ua2.i);
  const float al1 = ua1.f;
  const float al2 = ua2.f;

  // F tile: 16 rows x 64 -> LDS (coalesced 2KB read), wave-private (DS in-order)
#pragma unroll
  for (int jj = 0; jj < 2; ++jj) {
    const int idx = jj * 64 + lane;
    const int row = idx >> 3, c8 = (idx & 7) * 8;
    s8v v = *(const s8v*)(F + (size_t)(nbase + row) * 64 + c8);
    *(s8v*)(ft + row * FSTR + c8) = v;
  }

  f4v acc[4];
#pragma unroll
  for (int ftx = 0; ftx < 4; ++ftx) acc[ftx] = (f4v){0.f, 0.f, 0.f, 0.f};

#define LOADW(c0, W0, W1)                                            \
  { W0 = ebuf[(c0) + r]; W1 = ebuf[(c0) + 16 + r]; }
#define ISSUEG(W0, W1, GA0, GB0, GA1, GB1)                           \
  { unsigned s0 = ((unsigned)(W0)) >> 9, s1 = ((unsigned)(W1)) >> 9; \
    s0 = s0 < NN ? s0 : 0u; s1 = s1 < NN ? s1 : 0u;                  \
    GA0 = *(const u4v*)(G + (size_t)s0 * 64 + q * 8);                \
    GB0 = *(const u4v*)(G + (size_t)s0 * 64 + 32 + q * 8);           \
    GA1 = *(const u4v*)(G + (size_t)s1 * 64 + q * 8);                \
    GB1 = *(const u4v*)(G + (size_t)s1 * 64 + 32 + q * 8); }

  if (start < end) {
    int w0c, w1c, w0n, w1n;
    u4v ga0c, gb0c, ga1c, gb1c, ga0n, gb0n, ga1n, gb1n;
    LOADW(start, w0c, w1c);
    ISSUEG(w0c, w1c, ga0c, gb0c, ga1c, gb1c);
    LOADW(start + 32, w0n, w1n);

    for (int c0 = start; c0 < end; c0 += 32) {
      const int dl0 = w0c & 15, dl1 = w1c & 15;
      if (q == 0) {
        db[r]      = (unsigned short)((c0 + r < end) ? dl0 : 0xFF);
        db[16 + r] = (unsigned short)((c0 + 16 + r < end) ? dl1 : 0xFF);
      }
      // F rows from LDS tile
      u4v fa0 = *(const u4v*)(ft + dl0 * FSTR + q * 8);
      u4v fb0 = *(const u4v*)(ft + dl0 * FSTR + 32 + q * 8);
      u4v fa1 = *(const u4v*)(ft + dl1 * FSTR + q * 8);
      u4v fb1 = *(const u4v*)(ft + dl1 * FSTR + 32 + q * 8);

      union { u4v u; s8v s; } P00, P01, P10, P11;
#pragma unroll
      for (int j = 0; j < 4; ++j) {
        P00.u[j] = h1pair(fa0[j], ga0c[j], al1);
        P01.u[j] = h1pair(fb0[j], gb0c[j], al1);
        P10.u[j] = h1pair(fa1[j], ga1c[j], al1);
        P11.u[j] = h1pair(fb1[j], gb1c[j], al1);
      }

      // G registers consumed -> launch next chunk's gathers + future words
      ISSUEG(w0n, w1n, ga0n, gb0n, ga1n, gb1n);
      int w0f, w1f;
      LOADW(c0 + 64, w0f, w1f);

      // S^T indicator A-frag: A[m=node=r][k=edge=q*8+j], packed build:
      // per dword (2 dlocs): x = dv ^ (r|r<<16); halves are 0 iff match;
      // t = pk_sub_i16(pk_min_u16(x,1), 1) = 0xFFFF iff match; & bf16(1.0).
      u4v dvw = *(const u4v*)(db + q * 8);
      const unsigned rr = (unsigned)r * 0x00010001u;
      union { unsigned w[4]; s8v s; } sAu;
#pragma unroll
      for (int k = 0; k < 4; ++k) {
        unsigned x = dvw[k] ^ rr;
        unsigned m, t;
        asm("v_pk_min_u16 %0, %1, %2" : "=v"(m) : "v"(x), "s"(0x00010001u));
        asm("v_pk_sub_i16 %0, %1, %2" : "=v"(t) : "v"(m), "s"(0x00010001u));
        sAu.w[k] = t & 0x3F803F80u;
      }
      const s8v sA = sAu.s;

      // Swapped h2-MFMA: D[m=edge][n=feat]. Lane (q,r) holds edges
      // q*4+rg (c) and 16+q*4+rg (d) at feat ot*16+r. cvt_pk packs edge
      // pairs; permlane32+16 swaps turn quarters (A0,A1,A2,A3)x(B0..B3)
      // into (A0,A2,B0,B2) / (A1,A3,B1,B3) = agg B-frag dwords.
#pragma unroll
      for (int ot = 0; ot < 4; ++ot) {
        const float bb = b2c[ot];
        const f4v binit = {bb, bb, bb, bb};
        f4v c = binit;
        c = MFMA16(P00.s, W2T[0][ot], c);
        c = MFMA16(P01.s, W2T[1][ot], c);
        f4v d = binit;
        d = MFMA16(P10.s, W2T[0][ot], d);
        d = MFMA16(P11.s, W2T[1][ot], d);
        f4v cm, dm;
#pragma unroll
        for (int rg = 0; rg < 4; ++rg) {
          cm[rg] = fmaxf(c[rg], al2 * c[rg]);
          dm[rg] = fmaxf(d[rg], al2 * d[rg]);
        }
        unsigned pc0, pc1, pd0, pd1;
        asm("v_cvt_pk_bf16_f32 %0, %1, %2" : "=v"(pc0) : "v"(cm.x), "v"(cm.y));
        asm("v_cvt_pk_bf16_f32 %0, %1, %2" : "=v"(pc1) : "v"(cm.z), "v"(cm.w));
        asm("v_cvt_pk_bf16_f32 %0, %1, %2" : "=v"(pd0) : "v"(dm.x), "v"(dm.y));
        asm("v_cvt_pk_bf16_f32 %0, %1, %2" : "=v"(pd1) : "v"(dm.z), "v"(dm.w));
        // (x,y) -> x=(x.lo,y.lo), y=(x.hi,y.hi)
        asm("v_permlane32_swap_b32 %0, %1" : "+v"(pc0), "+v"(pd0));
        // (x,y) -> x=(x.q0,y.q0,x.q2,y.q2), y=(x.q1,y.q1,x.q3,y.q3)
        asm("v_permlane16_swap_b32 %0, %1" : "+v"(pc0), "+v"(pd0));
        asm("v_permlane32_swap_b32 %0, %1" : "+v"(pc1), "+v"(pd1));
        asm("v_permlane16_swap_b32 %0, %1" : "+v"(pc1), "+v"(pd1));
        union { unsigned w[4]; s8v s; } Bf;
        Bf.w[0] = pc0;  // edges q*8+0,1
        Bf.w[1] = pc1;  // edges q*8+2,3
        Bf.w[2] = pd0;  // edges q*8+4,5
        Bf.w[3] = pd1;  // edges q*8+6,7
        acc[ot] = MFMA16(sA, Bf.s, acc[ot]);
      }

      // rotate pipeline
      w0c = w0n; w1c = w1n; w0n = w0f; w1n = w1f;
      ga0c = ga0n; gb0c = gb0n; ga1c = ga1n; gb1c = gb1n;
    }
  }
#undef LOADW
#undef ISSUEG

  // flush: one bf16 store per (node, feature)
#pragma unroll
  for (int ftx = 0; ftx < 4; ++ftx)
#pragma unroll
    for (int rg = 0; rg < 4; ++rg) {
      const int node = nbase + q * 4 + rg;
      aggb[(size_t)node * 64 + ftx * 16 + r] = f2bf(acc[ftx][rg]);
    }
}

// ---------------------------------------------------------------------------
// Node MLP: z = prelu(prelu(cat(x,agg) @ W3 + b3) @ W4 + b4, a_blk)
// ---------------------------------------------------------------------------
__global__ __launch_bounds__(256) void node_mlp_kernel(
    const unsigned short* __restrict__ XB,
    const unsigned short* __restrict__ aggb,
    const unsigned short* __restrict__ pack,
    const float* __restrict__ b3, const float* __restrict__ a3p,
    const float* __restrict__ b4, const float* __restrict__ ablkp,
    unsigned short* __restrict__ zb,
    float* __restrict__ part)
{
  const int lane = threadIdx.x & 63;
  const int wv   = threadIdx.x >> 6;
  const int q    = lane >> 4;
  const int r    = lane & 15;
  const int nw   = gridDim.x * 4;
  const int wid  = blockIdx.x * 4 + wv;

  s8v B3f[4][4];
  s8v B4f[2][4];
#pragma unroll
  for (int kk = 0; kk < 4; ++kk)
#pragma unroll
    for (int nt = 0; nt < 4; ++nt)
      B3f[kk][nt] = ldfrag(pack, 24 + kk * 4 + nt, lane);
#pragma unroll
  for (int kk = 0; kk < 2; ++kk)
#pragma unroll
    for (int nt = 0; nt < 4; ++nt)
      B4f[kk][nt] = ldfrag(pack, 40 + kk * 4 + nt, lane);

  float bias3[4], bias4[4];
#pragma unroll
  for (int nt = 0; nt < 4; ++nt) { bias3[nt] = b3[nt * 16 + r]; bias4[nt] = b4[nt * 16 + r]; }
  const float al3 = a3p[0];
  const float alb = ablkp[0];

  __shared__ __align__(16) unsigned short hbuf[4][16 * 72];
  unsigned short* hb = hbuf[wv];

  float bs[4] = {0.f, 0.f, 0.f, 0.f};
  float bq[4] = {0.f, 0.f, 0.f, 0.f};

  for (int t = wid; t < NN / 16; t += nw) {
    const int n = t * 16 + r;
    const s8v* xn = (const s8v*)(XB + (size_t)n * 64);
    const s8v* an = (const s8v*)(aggb + (size_t)n * 64);
    s8v a0  = xn[q];
    s8v a1v = xn[q + 4];
    s8v a2v = an[q];
    s8v a3v = an[q + 4];

    f4v acc[4];
#pragma unroll
    for (int nt = 0; nt < 4; ++nt) {
      f4v c = {0.f, 0.f, 0.f, 0.f};
      c = MFMA16(a0,  B3f[0][nt], c);
      c = MFMA16(a1v, B3f[1][nt], c);
      c = MFMA16(a2v, B3f[2][nt], c);
      c = MFMA16(a3v, B3f[3][nt], c);
      acc[nt] = c;
    }

#pragma unroll
    for (int nt = 0; nt < 4; ++nt)
#pragma unroll
      for (int rg = 0; rg < 4; ++rg) {
        float v = prelu_m(acc[nt][rg] + bias3[nt], al3);
        hb[(q * 4 + rg) * 72 + nt * 16 + r] = f2bf(v);
      }
    s8v p0 = *(const s8v*)(hb + r * 72 + q * 8);
    s8v p1 = *(const s8v*)(hb + r * 72 + 32 + q * 8);

    f4v acc2[4];
#pragma unroll
    for (int nt = 0; nt < 4; ++nt) {
      f4v c = {0.f, 0.f, 0.f, 0.f};
      c = MFMA16(p0, B4f[0][nt], c);
      c = MFMA16(p1, B4f[1][nt], c);
      acc2[nt] = c;
    }

#pragma unroll
    for (int nt = 0; nt < 4; ++nt)
#pragma unroll
      for (int rg = 0; rg < 4; ++rg) {
        float v = prelu_m(acc2[nt][rg] + bias4[nt], alb);
        const int row = t * 16 + q * 4 + rg;
        zb[(size_t)row * 64 + nt * 16 + r] = f2bf(v);
        bs[nt] += v;
        bq[nt] += v * v;
      }
  }

#pragma unroll
  for (int nt = 0; nt < 4; ++nt) {
    float s = bs[nt];
    s += __shfl_xor(s, 16, 64);
    s += __shfl_xor(s, 32, 64);
    float ss = bq[nt];
    ss += __shfl_xor(ss, 16, 64);
    ss += __shfl_xor(ss, 32, 64);
    if (q == 0) {
      atomicAdd(&part[nt * 16 + r], s);
      atomicAdd(&part[64 + nt * 16 + r], ss);
    }
  }
}

// ---------------------------------------------------------------------------
// BatchNorm finalize: reads z (bf16 scratch), writes d_out (f32)
// ---------------------------------------------------------------------------
__global__ __launch_bounds__(256) void bn_kernel(
    const unsigned short* __restrict__ zb,
    float* __restrict__ out,
    const float* __restrict__ part,
    const float* __restrict__ gamma,
    const float* __restrict__ beta)
{
  const size_t i = (size_t)blockIdx.x * blockDim.x + threadIdx.x;
  if (i * 4 >= (size_t)NN * 64) return;
  ushort4 v = ((const ushort4*)zb)[i];
  unsigned short e[4] = {v.x, v.y, v.z, v.w};
  float o[4];
  const int f0 = (int)((i * 4) & 63);
  const float inv_n = 1.0f / (float)NN;
#pragma unroll
  for (int j = 0; j < 4; ++j) {
    const int f = f0 + j;
    const float mean = part[f] * inv_n;
    const float var  = part[64 + f] * inv_n - mean * mean;
    const float sc = rsqrtf(var + BN_EPS) * gamma[f];
    const float sh = beta[f] - mean * sc;
    o[j] = bf2f(e[j]) * sc + sh;
  }
  ((float4*)out)[i] = make_float4(o[0], o[1], o[2], o[3]);
}

extern "C" void kernel_launch(void* const* d_in, const int* in_sizes, int n_in,
                              void* d_out, int out_size, void* d_ws, size_t ws_size,
                              hipStream_t stream) {
  const float* x  = (const float*)d_in[0];
  const int* ei   = (const int*)d_in[1];
  const float* W1 = (const float*)d_in[2];
  const float* b1 = (const float*)d_in[3];
  const float* a1 = (const float*)d_in[4];
  const float* W2 = (const float*)d_in[5];
  const float* b2 = (const float*)d_in[6];
  const float* a2 = (const float*)d_in[7];
  const float* W3 = (const float*)d_in[8];
  const float* b3 = (const float*)d_in[9];
  const float* a3 = (const float*)d_in[10];
  const float* W4 = (const float*)d_in[11];
  const float* b4 = (const float*)d_in[12];
  const float* ab = (const float*)d_in[13];
  const float* gm = (const float*)d_in[14];
  const float* bt = (const float*)d_in[15];

  float* part          = (float*)d_ws;                   // [128] f32
  unsigned short* aggb = (unsigned short*)(part + 128);  // [NN*64] bf16
  unsigned short* F    = aggb + (size_t)NN * 64;         // [NN*64] bf16 (+b1)
  unsigned short* G    = F + (size_t)NN * 64;            // [NN*64] bf16
  unsigned short* XB   = G + (size_t)NN * 64;            // [NN*64] bf16
  unsigned short* zb   = XB + (size_t)NN * 64;           // [NN*64] bf16
  int* cursor          = (int*)(zb + (size_t)NN * 64);   // [6256] fine counts
  int* ebuf            = cursor + 6256;                  // [NBKT*FCAP + 128]
  unsigned short* pack = (unsigned short*)(ebuf + (size_t)NBKT * FCAP + 128);
  float* out           = (float*)d_out;

  const int* srcp = ei;        // edge_index[0] = src (x_j)
  const int* dstp = ei + NE;   // edge_index[1] = dst (x_i)

  hipMemsetAsync(cursor, 0, (size_t)NBKT * sizeof(int), stream);
  pack_kernel<<<dim3(1), dim3(256), 0, stream>>>(W1, W2, W3, W4, pack, part);
  pre_gemm_kernel<<<dim3(391), dim3(256), 0, stream>>>(x, pack, b1, F, G, XB);
  scatter_kernel<<<dim3(NE / 256), dim3(256), 0, stream>>>(srcp, dstp, cursor, ebuf);
  edge_agg_kernel<<<dim3((NBKT + 3) / 4), dim3(256), 0, stream>>>(
      F, G, ebuf, cursor, pack, a1, b2, a2, aggb);
  node_mlp_kernel<<<dim3(391), dim3(256), 0, stream>>>(
      XB, aggb, pack, b3, a3, b4, ab, zb, part);
  bn_kernel<<<dim3(6250), dim3(256), 0, stream>>>(zb, out, part, gm, bt);
}

// Round 5
// 263.099 us; speedup vs baseline: 1.1893x; 1.1893x over previous
//
#include <hip/hip_runtime.h>

#define NN 100000
#define NE 1600000
#define BN_EPS 1e-5f
#define NBKT 6250         // fine buckets of 16 nodes (g = dst>>4)
#define CB 392            // coarse buckets of 256 nodes (cb = dst>>8; 391 used)
#define SCAP 4864         // slab capacity per coarse bucket (mean 4096, +12 sigma)
#define CPAD 16           // cursor stride in ints (64B)
#define NBLKA 400         // scatter blocks (fused kernel, blockIdx < NBLKA)
#define NPREB 391         // pre_gemm blocks (fused kernel, blockIdx >= NBLKA)
#define EPA 4000          // edges per scatter block (400*4000 = NE)
#define FSTR 72           // LDS F-tile row stride in shorts (144B rows, 16B-aligned)
#define NFRAG 48          // packed weight fragments

typedef short s8v __attribute__((ext_vector_type(8)));
typedef float f4v __attribute__((ext_vector_type(4)));
typedef float f2v __attribute__((ext_vector_type(2)));
typedef unsigned u4v __attribute__((ext_vector_type(4)));

__device__ __forceinline__ float bf2f(unsigned short u) {
  union { unsigned u; float f; } v; v.u = ((unsigned)u) << 16; return v.f;
}
__device__ __forceinline__ unsigned fbits(float f) {
  union { float f; unsigned u; } v; v.f = f; return v.u;
}
__device__ __forceinline__ float bcast(unsigned u) {
  union { unsigned u; float f; } v; v.u = u; return v.f;
}
// round-half-up bf16 (ties differ from RNE with prob 2^-16 — negligible)
__device__ __forceinline__ unsigned short f2bf(float f) {
  return (unsigned short)((fbits(f) + 0x8000u) >> 16);
}
__device__ __forceinline__ s8v ldfrag(const unsigned short* __restrict__ pack,
                                      int f, int lane) {
  return *(const s8v*)(pack + ((size_t)f * 64 + lane) * 8);
}
// prelu(x) = max(x, a*x) — exact for 0 <= a <= 1 (a == 0.25 here)
__device__ __forceinline__ float prelu_m(float x, float a) { return fmaxf(x, a * x); }

// h1 on one dword pair (2 bf16 elems of F and G); RNE pack via v_cvt_pk_bf16_f32
__device__ __forceinline__ unsigned h1pair(unsigned fd, unsigned gd, float al) {
  f2v fv = { bcast(fd << 16), bcast(fd & 0xFFFF0000u) };
  f2v gv = { bcast(gd << 16), bcast(gd & 0xFFFF0000u) };
  f2v s = fv + gv;
  f2v t = s * al;
  float m0 = fmaxf(s.x, t.x);
  float m1 = fmaxf(s.y, t.y);
  unsigned rr;
  asm("v_cvt_pk_bf16_f32 %0, %1, %2" : "=v"(rr) : "v"(m0), "v"(m1));
  return rr;
}

#define MFMA16(a, b, c) __builtin_amdgcn_mfma_f32_16x16x32_bf16((a), (b), (c), 0, 0, 0)

// ---------------------------------------------------------------------------
// Weight pack (one-shot) + BN-partial zeroing.
// frag map: 0..7 W1 top | 8..15 W1 bot | 16..23 W2 | 24..39 W3 | 40..47 W4
// ---------------------------------------------------------------------------
__global__ __launch_bounds__(256) void pack_kernel(
    const float* __restrict__ W1, const float* __restrict__ W2,
    const float* __restrict__ W3, const float* __restrict__ W4,
    unsigned short* __restrict__ pack, float* __restrict__ part)
{
  if (threadIdx.x < 128) part[threadIdx.x] = 0.f;
  for (int it = threadIdx.x; it < NFRAG * 64; it += 256) {
    const int f = it >> 6;
    const int lane = it & 63;
    const int q = lane >> 4, r = lane & 15;
    const float* src; int rowoff, fi;
    if (f < 8)       { src = W1; rowoff = 0;  fi = f; }
    else if (f < 16) { src = W1; rowoff = 64; fi = f - 8; }
    else if (f < 24) { src = W2; rowoff = 0;  fi = f - 16; }
    else if (f < 40) { src = W3; rowoff = 0;  fi = f - 24; }
    else             { src = W4; rowoff = 0;  fi = f - 40; }
    const int kk = fi >> 2, nt = fi & 3;
    unsigned short tmp[8];
#pragma unroll
    for (int j = 0; j < 8; ++j)
      tmp[j] = f2bf(src[(size_t)(rowoff + kk * 32 + q * 8 + j) * 64 + nt * 16 + r]);
    *(s8v*)(pack + ((size_t)f * 64 + lane) * 8) = *(const s8v*)tmp;
  }
}

// ---------------------------------------------------------------------------
// FUSED: edge scatter (blocks 0..NBLKA-1) || pre-GEMM (blocks NBLKA..).
// The two phases are data-independent (scatter: edge_index only; pre_gemm:
// x + weights only) — grid partition overlaps latency-bound scatter with
// MFMA-bound pre_gemm. Scatter: per-block LDS hist -> one returning atomic
// per (block,bucket) reserves a coalesced run -> LDS-cursor placement.
// word = (src << 9) | (dst & 511). Pre-GEMM: F = X@W1top + b1, G = X@W1bot,
// XB = bf16(X).
// ---------------------------------------------------------------------------
__global__ __launch_bounds__(256) void pre_scatter_kernel(
    const float* __restrict__ x, const unsigned short* __restrict__ pack,
    const float* __restrict__ b1,
    unsigned short* __restrict__ F, unsigned short* __restrict__ G,
    unsigned short* __restrict__ XB,
    const int* __restrict__ srcp, const int* __restrict__ dstp,
    int* __restrict__ cursor, int* __restrict__ ebufA)
{
  __shared__ int lh[CB];
  __shared__ int lbase[CB];

  if (blockIdx.x < NBLKA) {
    // ---- scatter phase ----
    const int t = threadIdx.x;
    for (int i = t; i < CB; i += 256) lh[i] = 0;
    __syncthreads();
    const int base = blockIdx.x * EPA;
    for (int o = t; o < EPA; o += 256)
      atomicAdd(&lh[dstp[base + o] >> 8], 1);
    __syncthreads();
    for (int i = t; i < CB; i += 256) {
      const int c = lh[i];
      lbase[i] = c ? atomicAdd(&cursor[i * CPAD], c) : 0;
      lh[i] = 0;
    }
    __syncthreads();
    for (int o = t; o < EPA; o += 256) {
      const int d = dstp[base + o];
      const int s = srcp[base + o];
      const int cb = d >> 8;
      const int p = atomicAdd(&lh[cb], 1);
      ebufA[(size_t)cb * SCAP + lbase[cb] + p] = (s << 9) | (d & 511);
    }
    return;
  }

  // ---- pre_gemm phase ----
  const int lane = threadIdx.x & 63;
  const int wv   = threadIdx.x >> 6;
  const int q    = lane >> 4;
  const int r    = lane & 15;
  const int nw   = NPREB * 4;
  const int wid  = (blockIdx.x - NBLKA) * 4 + wv;

  s8v Bt[2][4], Bb[2][4];
#pragma unroll
  for (int kk = 0; kk < 2; ++kk)
#pragma unroll
    for (int nt = 0; nt < 4; ++nt) {
      Bt[kk][nt] = ldfrag(pack, kk * 4 + nt, lane);
      Bb[kk][nt] = ldfrag(pack, 8 + kk * 4 + nt, lane);
    }
  float b1c[4];
#pragma unroll
  for (int nt = 0; nt < 4; ++nt) b1c[nt] = b1[nt * 16 + r];

  for (int t = wid; t < NN / 16; t += nw) {
    const int n = t * 16 + r;
    const f4v* xp = (const f4v*)(x + (size_t)n * 64);
    f4v x0 = xp[q * 2],     x1 = xp[q * 2 + 1];
    f4v x2 = xp[8 + q * 2], x3 = xp[8 + q * 2 + 1];
    s8v a0, a1v;
#pragma unroll
    for (int j = 0; j < 4; ++j) {
      a0[j]      = (short)f2bf(x0[j]);
      a0[4 + j]  = (short)f2bf(x1[j]);
      a1v[j]     = (short)f2bf(x2[j]);
      a1v[4 + j] = (short)f2bf(x3[j]);
    }
    *(s8v*)(XB + (size_t)n * 64 + q * 8)      = a0;
    *(s8v*)(XB + (size_t)n * 64 + 32 + q * 8) = a1v;

    f4v aF[4], aG[4];
#pragma unroll
    for (int nt = 0; nt < 4; ++nt) {
      f4v c = {0.f, 0.f, 0.f, 0.f};
      c = MFMA16(a0,  Bt[0][nt], c);
      c = MFMA16(a1v, Bt[1][nt], c);
      aF[nt] = c;
      f4v d = {0.f, 0.f, 0.f, 0.f};
      d = MFMA16(a0,  Bb[0][nt], d);
      d = MFMA16(a1v, Bb[1][nt], d);
      aG[nt] = d;
    }
#pragma unroll
    for (int nt = 0; nt < 4; ++nt)
#pragma unroll
      for (int rg = 0; rg < 4; ++rg) {
        const size_t idx = (size_t)(t * 16 + q * 4 + rg) * 64 + nt * 16 + r;
        F[idx] = f2bf(aF[nt][rg] + b1c[nt]);
        G[idx] = f2bf(aG[nt][rg]);
      }
  }
}

// ---------------------------------------------------------------------------
// Pass B: one block per coarse slab (392 blocks = 2x the old 196);
// counting-sort ~4.1K edges into 16 fine buckets; emits absolute offsets
// fofs2[cb][0..16] into slab-addressed ebuf (dense within the slab).
// ---------------------------------------------------------------------------
__global__ __launch_bounds__(256) void sort_b_kernel(
    const int* __restrict__ ebufA, const int* __restrict__ cursor,
    int* __restrict__ fofs2, int* __restrict__ ebuf)
{
  __shared__ int lh[4][16];
  __shared__ int cur[16];
  const int cb = blockIdx.x;
  int cnt = cursor[cb * CPAD];
  cnt = cnt < SCAP ? cnt : SCAP;
  const int base = cb * SCAP;
  const int t = threadIdx.x;
  const int wv = t >> 6;
  if (t < 64) lh[t >> 4][t & 15] = 0;
  __syncthreads();
  for (int i = t; i < cnt; i += 256)
    atomicAdd(&lh[wv][(ebufA[base + i] >> 4) & 15], 1);
  __syncthreads();
  if (t == 0) {
    int run = base;
    for (int fb = 0; fb < 16; ++fb) {
      const int v = lh[0][fb] + lh[1][fb] + lh[2][fb] + lh[3][fb];
      cur[fb] = run;
      fofs2[cb * 17 + fb] = run;
      run += v;
    }
    fofs2[cb * 17 + 16] = run;
  }
  __syncthreads();
  for (int i = t; i < cnt; i += 256) {
    const int w = ebufA[base + i];
    const int p = atomicAdd(&cur[(w >> 4) & 15], 1);
    ebuf[p] = w;
  }
}

// ---------------------------------------------------------------------------
// Edge MLP + aggregation: one wave per 16-node fine bucket. RMW-free.
// In-register h2 (swapped MFMA + cvt_pk + permlane32/16), packed sA build,
// unclamped LOADW (slack reads masked by dloc; src index clamped < NN).
// ---------------------------------------------------------------------------
__global__ __launch_bounds__(256) void edge_agg_kernel(
    const unsigned short* __restrict__ F, const unsigned short* __restrict__ G,
    const int* __restrict__ ebuf, const int* __restrict__ fofs2,
    const unsigned short* __restrict__ pack,
    const float* __restrict__ a1p,
    const float* __restrict__ b2, const float* __restrict__ a2p,
    unsigned short* __restrict__ aggb)
{
  const int lane = threadIdx.x & 63;
  const int wv   = threadIdx.x >> 6;
  const int q    = lane >> 4;
  const int r    = lane & 15;

  __shared__ __align__(16) unsigned short ftl[4][16 * FSTR];   // per-wave F tile
  __shared__ __align__(16) unsigned short dbf[4][32];          // per-wave dloc
  unsigned short* ft = ftl[wv];
  unsigned short* db = dbf[wv];

  const int g = blockIdx.x * 4 + wv;
  if (g >= NBKT) return;                      // no block barriers below: safe

  const int cb = g >> 4, fb = g & 15;
  const int start = fofs2[cb * 17 + fb];
  const int end   = fofs2[cb * 17 + fb + 1];
  const int nbase = g * 16;

  s8v W2T[2][4];
#pragma unroll
  for (int kk = 0; kk < 2; ++kk)
#pragma unroll
    for (int ot = 0; ot < 4; ++ot)
      W2T[kk][ot] = ldfrag(pack, 16 + kk * 4 + ot, lane);

  // bias for swapped MFMA: C[row=edge][col=feat] -> per-lane scalar per ot
  float b2c[4];
#pragma unroll
  for (int ot = 0; ot < 4; ++ot) b2c[ot] = b2[ot * 16 + r];

  // uniform scalars -> SGPR
  union { float f; int i; } ua1, ua2;
  ua1.f = a1p[0]; ua1.i = __builtin_amdgcn_readfirstlane(ua1.i);
  ua2.f = a2p[0]; ua2.i = __builtin_amdgcn_readfirstlane(ua2.i);
  const float al1 = ua1.f;
  const float al2 = ua2.f;

  // F tile: 16 rows x 64 -> LDS (coalesced 2KB read), wave-private (DS in-order)
#pragma unroll
  for (int jj = 0; jj < 2; ++jj) {
    const int idx = jj * 64 + lane;
    const int row = idx >> 3, c8 = (idx & 7) * 8;
    s8v v = *(const s8v*)(F + (size_t)(nbase + row) * 64 + c8);
    *(s8v*)(ft + row * FSTR + c8) = v;
  }

  f4v acc[4];
#pragma unroll
  for (int ftx = 0; ftx < 4; ++ftx) acc[ftx] = (f4v){0.f, 0.f, 0.f, 0.f};

#define LOADW(c0, W0, W1)                                            \
  { W0 = ebuf[(c0) + r]; W1 = ebuf[(c0) + 16 + r]; }
#define ISSUEG(W0, W1, GA0, GB0, GA1, GB1)                           \
  { unsigned s0 = ((unsigned)(W0)) >> 9, s1 = ((unsigned)(W1)) >> 9; \
    s0 = s0 < NN ? s0 : 0u; s1 = s1 < NN ? s1 : 0u;                  \
    GA0 = *(const u4v*)(G + (size_t)s0 * 64 + q * 8);                \
    GB0 = *(const u4v*)(G + (size_t)s0 * 64 + 32 + q * 8);           \
    GA1 = *(const u4v*)(G + (size_t)s1 * 64 + q * 8);                \
    GB1 = *(const u4v*)(G + (size_t)s1 * 64 + 32 + q * 8); }

  if (start < end) {
    int w0c, w1c, w0n, w1n;
    u4v ga0c, gb0c, ga1c, gb1c, ga0n, gb0n, ga1n, gb1n;
    LOADW(start, w0c, w1c);
    ISSUEG(w0c, w1c, ga0c, gb0c, ga1c, gb1c);
    LOADW(start + 32, w0n, w1n);

    for (int c0 = start; c0 < end; c0 += 32) {
      const int dl0 = w0c & 15, dl1 = w1c & 15;
      if (q == 0) {
        db[r]      = (unsigned short)((c0 + r < end) ? dl0 : 0xFF);
        db[16 + r] = (unsigned short)((c0 + 16 + r < end) ? dl1 : 0xFF);
      }
      // F rows from LDS tile
      u4v fa0 = *(const u4v*)(ft + dl0 * FSTR + q * 8);
      u4v fb0 = *(const u4v*)(ft + dl0 * FSTR + 32 + q * 8);
      u4v fa1 = *(const u4v*)(ft + dl1 * FSTR + q * 8);
      u4v fb1 = *(const u4v*)(ft + dl1 * FSTR + 32 + q * 8);

      union { u4v u; s8v s; } P00, P01, P10, P11;
#pragma unroll
      for (int j = 0; j < 4; ++j) {
        P00.u[j] = h1pair(fa0[j], ga0c[j], al1);
        P01.u[j] = h1pair(fb0[j], gb0c[j], al1);
        P10.u[j] = h1pair(fa1[j], ga1c[j], al1);
        P11.u[j] = h1pair(fb1[j], gb1c[j], al1);
      }

      // G registers consumed -> launch next chunk's gathers + future words
      ISSUEG(w0n, w1n, ga0n, gb0n, ga1n, gb1n);
      int w0f, w1f;
      LOADW(c0 + 64, w0f, w1f);

      // S^T indicator A-frag: A[m=node=r][k=edge=q*8+j], packed build:
      // per dword (2 dlocs): x = dv ^ (r|r<<16); halves are 0 iff match;
      // t = pk_sub_i16(pk_min_u16(x,1), 1) = 0xFFFF iff match; & bf16(1.0).
      u4v dvw = *(const u4v*)(db + q * 8);
      const unsigned rr = (unsigned)r * 0x00010001u;
      union { unsigned w[4]; s8v s; } sAu;
#pragma unroll
      for (int k = 0; k < 4; ++k) {
        unsigned x = dvw[k] ^ rr;
        unsigned m, t;
        asm("v_pk_min_u16 %0, %1, %2" : "=v"(m) : "v"(x), "s"(0x00010001u));
        asm("v_pk_sub_i16 %0, %1, %2" : "=v"(t) : "v"(m), "s"(0x00010001u));
        sAu.w[k] = t & 0x3F803F80u;
      }
      const s8v sA = sAu.s;

      // Swapped h2-MFMA: D[m=edge][n=feat]. Lane (q,r) holds edges
      // q*4+rg (c) and 16+q*4+rg (d) at feat ot*16+r. cvt_pk packs edge
      // pairs; permlane32+16 swaps turn quarters (A0,A1,A2,A3)x(B0..B3)
      // into (A0,A2,B0,B2) / (A1,A3,B1,B3) = agg B-frag dwords.
#pragma unroll
      for (int ot = 0; ot < 4; ++ot) {
        const float bb = b2c[ot];
        const f4v binit = {bb, bb, bb, bb};
        f4v c = binit;
        c = MFMA16(P00.s, W2T[0][ot], c);
        c = MFMA16(P01.s, W2T[1][ot], c);
        f4v d = binit;
        d = MFMA16(P10.s, W2T[0][ot], d);
        d = MFMA16(P11.s, W2T[1][ot], d);
        f4v cm, dm;
#pragma unroll
        for (int rg = 0; rg < 4; ++rg) {
          cm[rg] = fmaxf(c[rg], al2 * c[rg]);
          dm[rg] = fmaxf(d[rg], al2 * d[rg]);
        }
        unsigned pc0, pc1, pd0, pd1;
        asm("v_cvt_pk_bf16_f32 %0, %1, %2" : "=v"(pc0) : "v"(cm.x), "v"(cm.y));
        asm("v_cvt_pk_bf16_f32 %0, %1, %2" : "=v"(pc1) : "v"(cm.z), "v"(cm.w));
        asm("v_cvt_pk_bf16_f32 %0, %1, %2" : "=v"(pd0) : "v"(dm.x), "v"(dm.y));
        asm("v_cvt_pk_bf16_f32 %0, %1, %2" : "=v"(pd1) : "v"(dm.z), "v"(dm.w));
        // (x,y) -> x=(x.lo,y.lo), y=(x.hi,y.hi)
        asm("v_permlane32_swap_b32 %0, %1" : "+v"(pc0), "+v"(pd0));
        // (x,y) -> x=(x.q0,y.q0,x.q2,y.q2), y=(x.q1,y.q1,x.q3,y.q3)
        asm("v_permlane16_swap_b32 %0, %1" : "+v"(pc0), "+v"(pd0));
        asm("v_permlane32_swap_b32 %0, %1" : "+v"(pc1), "+v"(pd1));
        asm("v_permlane16_swap_b32 %0, %1" : "+v"(pc1), "+v"(pd1));
        union { unsigned w[4]; s8v s; } Bf;
        Bf.w[0] = pc0;  // edges q*8+0,1
        Bf.w[1] = pc1;  // edges q*8+2,3
        Bf.w[2] = pd0;  // edges q*8+4,5
        Bf.w[3] = pd1;  // edges q*8+6,7
        acc[ot] = MFMA16(sA, Bf.s, acc[ot]);
      }

      // rotate pipeline
      w0c = w0n; w1c = w1n; w0n = w0f; w1n = w1f;
      ga0c = ga0n; gb0c = gb0n; ga1c = ga1n; gb1c = gb1n;
    }
  }
#undef LOADW
#undef ISSUEG

  // flush: one bf16 store per (node, feature)
#pragma unroll
  for (int ftx = 0; ftx < 4; ++ftx)
#pragma unroll
    for (int rg = 0; rg < 4; ++rg) {
      const int node = nbase + q * 4 + rg;
      aggb[(size_t)node * 64 + ftx * 16 + r] = f2bf(acc[ftx][rg]);
    }
}

// ---------------------------------------------------------------------------
// Node MLP: z = prelu(prelu(cat(x,agg) @ W3 + b3) @ W4 + b4, a_blk)
// ---------------------------------------------------------------------------
__global__ __launch_bounds__(256) void node_mlp_kernel(
    const unsigned short* __restrict__ XB,
    const unsigned short* __restrict__ aggb,
    const unsigned short* __restrict__ pack,
    const float* __restrict__ b3, const float* __restrict__ a3p,
    const float* __restrict__ b4, const float* __restrict__ ablkp,
    unsigned short* __restrict__ zb,
    float* __restrict__ part)
{
  const int lane = threadIdx.x & 63;
  const int wv   = threadIdx.x >> 6;
  const int q    = lane >> 4;
  const int r    = lane & 15;
  const int nw   = gridDim.x * 4;
  const int wid  = blockIdx.x * 4 + wv;

  s8v B3f[4][4];
  s8v B4f[2][4];
#pragma unroll
  for (int kk = 0; kk < 4; ++kk)
#pragma unroll
    for (int nt = 0; nt < 4; ++nt)
      B3f[kk][nt] = ldfrag(pack, 24 + kk * 4 + nt, lane);
#pragma unroll
  for (int kk = 0; kk < 2; ++kk)
#pragma unroll
    for (int nt = 0; nt < 4; ++nt)
      B4f[kk][nt] = ldfrag(pack, 40 + kk * 4 + nt, lane);

  float bias3[4], bias4[4];
#pragma unroll
  for (int nt = 0; nt < 4; ++nt) { bias3[nt] = b3[nt * 16 + r]; bias4[nt] = b4[nt * 16 + r]; }
  const float al3 = a3p[0];
  const float alb = ablkp[0];

  __shared__ __align__(16) unsigned short hbuf[4][16 * 72];
  unsigned short* hb = hbuf[wv];

  float bs[4] = {0.f, 0.f, 0.f, 0.f};
  float bq[4] = {0.f, 0.f, 0.f, 0.f};

  for (int t = wid; t < NN / 16; t += nw) {
    const int n = t * 16 + r;
    const s8v* xn = (const s8v*)(XB + (size_t)n * 64);
    const s8v* an = (const s8v*)(aggb + (size_t)n * 64);
    s8v a0  = xn[q];
    s8v a1v = xn[q + 4];
    s8v a2v = an[q];
    s8v a3v = an[q + 4];

    f4v acc[4];
#pragma unroll
    for (int nt = 0; nt < 4; ++nt) {
      f4v c = {0.f, 0.f, 0.f, 0.f};
      c = MFMA16(a0,  B3f[0][nt], c);
      c = MFMA16(a1v, B3f[1][nt], c);
      c = MFMA16(a2v, B3f[2][nt], c);
      c = MFMA16(a3v, B3f[3][nt], c);
      acc[nt] = c;
    }

#pragma unroll
    for (int nt = 0; nt < 4; ++nt)
#pragma unroll
      for (int rg = 0; rg < 4; ++rg) {
        float v = prelu_m(acc[nt][rg] + bias3[nt], al3);
        hb[(q * 4 + rg) * 72 + nt * 16 + r] = f2bf(v);
      }
    s8v p0 = *(const s8v*)(hb + r * 72 + q * 8);
    s8v p1 = *(const s8v*)(hb + r * 72 + 32 + q * 8);

    f4v acc2[4];
#pragma unroll
    for (int nt = 0; nt < 4; ++nt) {
      f4v c = {0.f, 0.f, 0.f, 0.f};
      c = MFMA16(p0, B4f[0][nt], c);
      c = MFMA16(p1, B4f[1][nt], c);
      acc2[nt] = c;
    }

#pragma unroll
    for (int nt = 0; nt < 4; ++nt)
#pragma unroll
      for (int rg = 0; rg < 4; ++rg) {
        float v = prelu_m(acc2[nt][rg] + bias4[nt], alb);
        const int row = t * 16 + q * 4 + rg;
        zb[(size_t)row * 64 + nt * 16 + r] = f2bf(v);
        bs[nt] += v;
        bq[nt] += v * v;
      }
  }

#pragma unroll
  for (int nt = 0; nt < 4; ++nt) {
    float s = bs[nt];
    s += __shfl_xor(s, 16, 64);
    s += __shfl_xor(s, 32, 64);
    float ss = bq[nt];
    ss += __shfl_xor(ss, 16, 64);
    ss += __shfl_xor(ss, 32, 64);
    if (q == 0) {
      atomicAdd(&part[nt * 16 + r], s);
      atomicAdd(&part[64 + nt * 16 + r], ss);
    }
  }
}

// ---------------------------------------------------------------------------
// BatchNorm finalize: reads z (bf16 scratch), writes d_out (f32)
// ---------------------------------------------------------------------------
__global__ __launch_bounds__(256) void bn_kernel(
    const unsigned short* __restrict__ zb,
    float* __restrict__ out,
    const float* __restrict__ part,
    const float* __restrict__ gamma,
    const float* __restrict__ beta)
{
  const size_t i = (size_t)blockIdx.x * blockDim.x + threadIdx.x;
  if (i * 4 >= (size_t)NN * 64) return;
  ushort4 v = ((const ushort4*)zb)[i];
  unsigned short e[4] = {v.x, v.y, v.z, v.w};
  float o[4];
  const int f0 = (int)((i * 4) & 63);
  const float inv_n = 1.0f / (float)NN;
#pragma unroll
  for (int j = 0; j < 4; ++j) {
    const int f = f0 + j;
    const float mean = part[f] * inv_n;
    const float var  = part[64 + f] * inv_n - mean * mean;
    const float sc = rsqrtf(var + BN_EPS) * gamma[f];
    const float sh = beta[f] - mean * sc;
    o[j] = bf2f(e[j]) * sc + sh;
  }
  ((float4*)out)[i] = make_float4(o[0], o[1], o[2], o[3]);
}

extern "C" void kernel_launch(void* const* d_in, const int* in_sizes, int n_in,
                              void* d_out, int out_size, void* d_ws, size_t ws_size,
                              hipStream_t stream) {
  const float* x  = (const float*)d_in[0];
  const int* ei   = (const int*)d_in[1];
  const float* W1 = (const float*)d_in[2];
  const float* b1 = (const float*)d_in[3];
  const float* a1 = (const float*)d_in[4];
  const float* W2 = (const float*)d_in[5];
  const float* b2 = (const float*)d_in[6];
  const float* a2 = (const float*)d_in[7];
  const float* W3 = (const float*)d_in[8];
  const float* b3 = (const float*)d_in[9];
  const float* a3 = (const float*)d_in[10];
  const float* W4 = (const float*)d_in[11];
  const float* b4 = (const float*)d_in[12];
  const float* ab = (const float*)d_in[13];
  const float* gm = (const float*)d_in[14];
  const float* bt = (const float*)d_in[15];

  float* part          = (float*)d_ws;                   // [128] f32
  unsigned short* aggb = (unsigned short*)(part + 128);  // [NN*64] bf16
  unsigned short* F    = aggb + (size_t)NN * 64;         // [NN*64] bf16 (+b1)
  unsigned short* G    = F + (size_t)NN * 64;            // [NN*64] bf16
  unsigned short* XB   = G + (size_t)NN * 64;            // [NN*64] bf16
  unsigned short* zb   = XB + (size_t)NN * 64;           // [NN*64] bf16
  int* cursor          = (int*)(zb + (size_t)NN * 64);   // [CB*CPAD] padded
  int* fofs2           = cursor + (size_t)CB * CPAD;     // [CB*17] (+pad)
  int* ebufA           = fofs2 + CB * 17 + 8;            // [CB*SCAP]
  int* ebuf            = ebufA + (size_t)CB * SCAP;      // [CB*SCAP + 128]
  unsigned short* pack = (unsigned short*)(ebuf + (size_t)CB * SCAP + 128);
  float* out           = (float*)d_out;

  const int* srcp = ei;        // edge_index[0] = src (x_j)
  const int* dstp = ei + NE;   // edge_index[1] = dst (x_i)

  hipMemsetAsync(cursor, 0, (size_t)CB * CPAD * sizeof(int), stream);
  pack_kernel<<<dim3(1), dim3(256), 0, stream>>>(W1, W2, W3, W4, pack, part);
  pre_scatter_kernel<<<dim3(NBLKA + NPREB), dim3(256), 0, stream>>>(
      x, pack, b1, F, G, XB, srcp, dstp, cursor, ebufA);
  sort_b_kernel<<<dim3(CB), dim3(256), 0, stream>>>(ebufA, cursor, fofs2, ebuf);
  edge_agg_kernel<<<dim3((NBKT + 3) / 4), dim3(256), 0, stream>>>(
      F, G, ebuf, fofs2, pack, a1, b2, a2, aggb);
  node_mlp_kernel<<<dim3(391), dim3(256), 0, stream>>>(
      XB, aggb, pack, b3, a3, b4, ab, zb, part);
  bn_kernel<<<dim3(6250), dim3(256), 0, stream>>>(zb, out, part, gm, bt);
}